// Round 6
// baseline (230.016 us; speedup 1.0000x reference)
//
#include <hip/hip_runtime.h>
#include <hip/hip_bf16.h>
#include <math.h>

#define Bn 8
#define Sn 2048
#define Hn 768
#define NROW 4096          // B * N_SPANS
#define SPAN_DIM 2688
#define NBIG 1536          // fused GEMM N (768 type-t | 768 sens-pre)
#define NTYPE 18
#define NSENS 4
#define WPAD 24            // padded per-k weight row (shorts), 48 B

// merged pre-kernel block partition
#define NB_PROP 4096
#define NB_SPAN 4096
#define NB_T    2016       // per big transpose (84 x 24 tiles of 32x32)
#define NB_SM   156        // small-weight prep (156*256 = 39936 elems)
#define NB_TOTAL (NB_PROP + NB_SPAN + 2 * NB_T + NB_SM)

typedef __attribute__((ext_vector_type(8))) short short8;
typedef __attribute__((ext_vector_type(4))) float floatx4;

__device__ __forceinline__ unsigned short f2bf(float x) {
    __hip_bfloat16 h = __float2bfloat16(x);
    return *reinterpret_cast<unsigned short*>(&h);
}

__device__ __forceinline__ float bfu(unsigned short u) {
    union { float f; unsigned int i; } v;
    v.i = ((unsigned int)u) << 16;
    return v.f;
}

__device__ __forceinline__ void glds16(const void* g, void* l) {
    __builtin_amdgcn_global_load_lds(
        (const __attribute__((address_space(1))) unsigned int*)g,
        (__attribute__((address_space(3))) unsigned int*)l, 16, 0, 0);
}

__device__ __forceinline__ float gelu_exact(float v) {
    return 0.5f * v * (1.f + erff(v * 0.70710678118654752f));
}

// ============ merged pre-kernel: proposal | span_rep | weight prep ============
__global__ __launch_bounds__(256) void pre_kernel(
    const float* __restrict__ hidden, const int* __restrict__ spans,
    const float* __restrict__ wemb,
    const float* __restrict__ Wp, const float* __restrict__ bp,
    const float* __restrict__ Wt1, const float* __restrict__ Ws1,
    const float* __restrict__ Wt2, const float* __restrict__ Ws2,
    float* __restrict__ out_prop, unsigned short* __restrict__ rep,
    unsigned short* __restrict__ WbigT,
    unsigned short* __restrict__ Wt2bf, unsigned short* __restrict__ Wtailbf,
    unsigned short* __restrict__ Ws2bf)
{
    __shared__ float tile[32][33];
    int id = blockIdx.x;
    int tid = threadIdx.x;

    if (id < NB_PROP) {
        // ---- proposal head: 4 rows per block ----
        int wave = tid >> 6, lane = tid & 63;
        int row = id * 4 + wave;
        const float4* h4 = (const float4*)(hidden + (size_t)row * Hn);
        float a0 = 0.f, a1 = 0.f, a2 = 0.f;
#pragma unroll
        for (int i = 0; i < 3; ++i) {
            int kc = i * 64 + lane;
            float4 h = h4[kc];
            const float* w = Wp + kc * 12;
            a0 += h.x * w[0] + h.y * w[3] + h.z * w[6] + h.w * w[9];
            a1 += h.x * w[1] + h.y * w[4] + h.z * w[7] + h.w * w[10];
            a2 += h.x * w[2] + h.y * w[5] + h.z * w[8] + h.w * w[11];
        }
#pragma unroll
        for (int off = 32; off; off >>= 1) {
            a0 += __shfl_xor(a0, off);
            a1 += __shfl_xor(a1, off);
            a2 += __shfl_xor(a2, off);
        }
        if (lane < 3) {
            float v = (lane == 0 ? a0 : (lane == 1 ? a1 : a2)) + bp[lane];
            out_prop[row * 3 + lane] = v;
        }
        return;
    }
    id -= NB_PROP;
    if (id < NB_SPAN) {
        // ---- span representation (threads 0..191 active) ----
        if (tid >= 192) return;
        int n = id;
        int b = n >> 9;
        int s = spans[n * 2 + 0];
        int e = spans[n * 2 + 1];
        int w = e - s + 1;
        const float4* hb4 = (const float4*)(hidden + (size_t)b * Sn * Hn);
        unsigned short* r = rep + (size_t)n * SPAN_DIM;
        float inv_w = 1.0f / (float)w;

        float4 sv = hb4[(size_t)s * 192 + tid];
        float4 ev = hb4[(size_t)e * 192 + tid];
        float4 p0 = make_float4(0.f, 0.f, 0.f, 0.f), p1 = p0, p2 = p0, p3 = p0;
        int rr = s;
        for (; rr + 3 <= e; rr += 4) {
            float4 h0 = hb4[(size_t)(rr + 0) * 192 + tid];
            float4 h1 = hb4[(size_t)(rr + 1) * 192 + tid];
            float4 h2 = hb4[(size_t)(rr + 2) * 192 + tid];
            float4 h3 = hb4[(size_t)(rr + 3) * 192 + tid];
            p0.x += h0.x; p0.y += h0.y; p0.z += h0.z; p0.w += h0.w;
            p1.x += h1.x; p1.y += h1.y; p1.z += h1.z; p1.w += h1.w;
            p2.x += h2.x; p2.y += h2.y; p2.z += h2.z; p2.w += h2.w;
            p3.x += h3.x; p3.y += h3.y; p3.z += h3.z; p3.w += h3.w;
        }
        for (; rr <= e; ++rr) {
            float4 h = hb4[(size_t)rr * 192 + tid];
            p0.x += h.x; p0.y += h.y; p0.z += h.z; p0.w += h.w;
        }
        float4 pv;
        pv.x = ((p0.x + p1.x) + (p2.x + p3.x)) * inv_w;
        pv.y = ((p0.y + p1.y) + (p2.y + p3.y)) * inv_w;
        pv.z = ((p0.z + p1.z) + (p2.z + p3.z)) * inv_w;
        pv.w = ((p0.w + p1.w) + (p2.w + p3.w)) * inv_w;

        *(ushort4*)&r[tid * 4] =
            make_ushort4(f2bf(sv.x), f2bf(sv.y), f2bf(sv.z), f2bf(sv.w));
        *(ushort4*)&r[Hn + tid * 4] =
            make_ushort4(f2bf(ev.x), f2bf(ev.y), f2bf(ev.z), f2bf(ev.w));
        *(ushort4*)&r[2 * Hn + tid * 4] =
            make_ushort4(f2bf(pv.x), f2bf(pv.y), f2bf(pv.z), f2bf(pv.w));
        if (tid < 96) {
            int wi = w > 63 ? 63 : w;
            float4 wv = ((const float4*)wemb)[wi * 96 + tid];
            *(ushort4*)&r[3 * Hn + tid * 4] =
                make_ushort4(f2bf(wv.x), f2bf(wv.y), f2bf(wv.z), f2bf(wv.w));
        }
        return;
    }
    id -= NB_SPAN;
    if (id < 2 * NB_T) {
        // ---- big weight transpose+cvt: W[2688][768] -> WbigT[z*768..][2688] ----
        int z = id / NB_T, l = id - z * NB_T;
        const float* W = (z == 0) ? Wt1 : Ws1;
        unsigned short* Wt = WbigT + (size_t)z * Hn * SPAN_DIM;
        int k0 = (l % 84) * 32, n0 = (l / 84) * 32;
        int tx = tid & 31, ty = tid >> 5;
#pragma unroll
        for (int i = 0; i < 32; i += 8)
            tile[ty + i][tx] = W[(size_t)(k0 + ty + i) * Hn + n0 + tx];
        __syncthreads();
#pragma unroll
        for (int i = 0; i < 32; i += 8)
            Wt[(size_t)(n0 + ty + i) * SPAN_DIM + k0 + tx] = f2bf(tile[tx][ty + i]);
        return;
    }
    id -= 2 * NB_T;
    {
        // ---- small k-major bf16 weights ----
        int idx = id * 256 + tid;
        const int N1 = Hn * WPAD;
        const int N2 = 2 * N1;
        const int N3 = N2 + Hn * NSENS;
        if (idx < N1) {
            int k = idx / WPAD, o = idx - k * WPAD;
            Wt2bf[idx] = (o < NTYPE) ? f2bf(Wt2[k * NTYPE + o]) : 0;
        } else if (idx < N2) {
            int j = idx - N1;
            int k = j / WPAD, o = j - k * WPAD;
            Wtailbf[j] = (o < NTYPE) ? f2bf(Ws1[(size_t)(SPAN_DIM + o) * Hn + k]) : 0;
        } else if (idx < N3) {
            int j = idx - N2;
            Ws2bf[j] = f2bf(Ws2[j]);
        }
    }
}

// ===== fused bf16 MFMA GEMM, double-buffered LDS + XCD-aware swizzle =====
// obuf = epilogue(rep @ WbigT^T); 128x64 tile, BK=64, flat 768-block grid.
__global__ __launch_bounds__(256, 3) void gemm_fused(
    const unsigned short* __restrict__ A,
    const unsigned short* __restrict__ Bt,
    const float* __restrict__ bt1, const float* __restrict__ bs1,
    float* __restrict__ obuf)
{
    const int BK = 64;
    __shared__ unsigned short As[2][128 * BK];   // 2 x 16 KB
    __shared__ unsigned short Bs[2][64 * BK];    // 2 x 8 KB

    int tid = threadIdx.x, wave = tid >> 6, lane = tid & 63;
    // XCD-aware swizzle: xcd = id & 7 owns 4 row-tiles x all 24 col-tiles
    int bid = blockIdx.x;
    int xcd = bid & 7, g = bid >> 3;
    int bx = xcd * 4 + (g / 24);    // 0..31 row tile (A stays in this XCD's L2)
    int by = g % 24;                // 0..23 col tile
    int m0 = bx * 128, n0 = by * 64;

    int wr = (wave >> 1) * 64;
    int wc = (wave & 1) * 32;
    int fr = lane & 15;
    int fc = lane >> 4;             // 0..3

    const unsigned short* gA[4];
#pragma unroll
    for (int j = 0; j < 4; ++j) {
        int d = tid + j * 256;
        int r = d >> 3, c = (d & 7) ^ (r & 7);
        gA[j] = A + (size_t)(m0 + r) * SPAN_DIM + c * 8;
    }
    const unsigned short* gB[2];
#pragma unroll
    for (int j = 0; j < 2; ++j) {
        int d = tid + j * 256;
        int r = d >> 3, c = (d & 7) ^ (r & 7);
        gB[j] = Bt + (size_t)(n0 + r) * SPAN_DIM + c * 8;
    }
    // wave-uniform LDS staging bases (lane*16B implicit in global_load_lds)
    int offA[4], offB[2];
#pragma unroll
    for (int j = 0; j < 4; ++j) offA[j] = j * 2048 + wave * 512;
#pragma unroll
    for (int j = 0; j < 2; ++j) offB[j] = j * 2048 + wave * 512;

    floatx4 acc[4][2] = {};

    // prologue: stage k0=0 into buffer 0
    glds16(gA[0], &As[0][offA[0]]);
    glds16(gA[1], &As[0][offA[1]]);
    glds16(gA[2], &As[0][offA[2]]);
    glds16(gA[3], &As[0][offA[3]]);
    glds16(gB[0], &Bs[0][offB[0]]);
    glds16(gB[1], &Bs[0][offB[1]]);

    const int NITER = SPAN_DIM / BK;   // 42
    for (int i = 0; i < NITER; ++i) {
        int cur = i & 1;
        __syncthreads();               // drains cur-buffer loads; frees other buffer
        if (i + 1 < NITER) {
            int k1 = (i + 1) * BK;
            int nxt = cur ^ 1;
            glds16(gA[0] + k1, &As[nxt][offA[0]]);
            glds16(gA[1] + k1, &As[nxt][offA[1]]);
            glds16(gA[2] + k1, &As[nxt][offA[2]]);
            glds16(gA[3] + k1, &As[nxt][offA[3]]);
            glds16(gB[0] + k1, &Bs[nxt][offB[0]]);
            glds16(gB[1] + k1, &Bs[nxt][offB[1]]);
        }
#pragma unroll
        for (int half = 0; half < 2; ++half) {
            int cb = half * 4 + fc;
            short8 af[4], bf[2];
#pragma unroll
            for (int ii = 0; ii < 4; ++ii) {
                int r = wr + ii * 16 + fr;
                af[ii] = *(const short8*)&As[cur][((r << 3) | (cb ^ (r & 7))) * 8];
            }
#pragma unroll
            for (int ii = 0; ii < 2; ++ii) {
                int r = wc + ii * 16 + fr;
                bf[ii] = *(const short8*)&Bs[cur][((r << 3) | (cb ^ (r & 7))) * 8];
            }
#pragma unroll
            for (int mi = 0; mi < 4; ++mi)
#pragma unroll
                for (int ni = 0; ni < 2; ++ni)
                    acc[mi][ni] = __builtin_amdgcn_mfma_f32_16x16x32_bf16(
                        af[mi], bf[ni], acc[mi][ni], 0, 0, 0);
        }
    }

    bool isT = (n0 < Hn);
    const float* bias = isT ? bt1 : (bs1 - Hn);
    int cr = (lane >> 4) * 4;
#pragma unroll
    for (int mi = 0; mi < 4; ++mi) {
#pragma unroll
        for (int ni = 0; ni < 2; ++ni) {
            int col = n0 + wc + ni * 16 + fr;
            float bv = bias[col];
#pragma unroll
            for (int r = 0; r < 4; ++r) {
                int row = m0 + wr + mi * 16 + cr + r;
                float v = acc[mi][ni][r] + bv;
                if (isT) v = gelu_exact(v);
                obuf[(size_t)row * NBIG + col] = v;
            }
        }
    }
}

// --- fused heads: coalesced k-major bf16 weights, lane owns k=lane*12..+11 ---
__global__ __launch_bounds__(256) void heads_kernel(
    const float* __restrict__ obuf, const unsigned short* __restrict__ Wt2bf,
    const float* __restrict__ bt2, const unsigned short* __restrict__ Wtailbf,
    const unsigned short* __restrict__ Ws2bf, const float* __restrict__ bs2,
    float* __restrict__ out_type, float* __restrict__ out_sens)
{
    int wave = threadIdx.x >> 6, lane = threadIdx.x & 63;
    int row = blockIdx.x * 4 + wave;
    const float* tr = obuf + (size_t)row * NBIG;

    float t[12];
    {
        const float4* t4 = (const float4*)(tr + lane * 12);
        float4 a = t4[0], b = t4[1], c = t4[2];
        t[0] = a.x; t[1] = a.y; t[2]  = a.z; t[3]  = a.w;
        t[4] = b.x; t[5] = b.y; t[6]  = b.z; t[7]  = b.w;
        t[8] = c.x; t[9] = c.y; t[10] = c.z; t[11] = c.w;
    }
    float acc[NTYPE] = {};
    const unsigned short* wp = Wt2bf + (size_t)lane * 12 * WPAD;
#pragma unroll
    for (int j = 0; j < 12; ++j) {
        short8 w0 = *(const short8*)(wp + j * WPAD);
        short8 w1 = *(const short8*)(wp + j * WPAD + 8);
        ushort4 w2 = *(const ushort4*)(wp + j * WPAD + 16);
        float tv = t[j];
#pragma unroll
        for (int o = 0; o < 8; ++o) acc[o] += tv * bfu((unsigned short)w0[o]);
#pragma unroll
        for (int o = 0; o < 8; ++o) acc[8 + o] += tv * bfu((unsigned short)w1[o]);
        acc[16] += tv * bfu(w2.x);
        acc[17] += tv * bfu(w2.y);
    }
#pragma unroll
    for (int o = 0; o < NTYPE; ++o)
#pragma unroll
        for (int off = 32; off; off >>= 1) acc[o] += __shfl_xor(acc[o], off);

    float mx = -1e30f;
#pragma unroll
    for (int o = 0; o < NTYPE; ++o) { acc[o] += bt2[o]; mx = fmaxf(mx, acc[o]); }
    {
        float lv = 0.f;
#pragma unroll
        for (int o = 0; o < NTYPE; ++o) lv = (lane == o) ? acc[o] : lv;
        if (lane < NTYPE) out_type[row * NTYPE + lane] = lv;
    }
    float pr[NTYPE], sum = 0.f;
#pragma unroll
    for (int o = 0; o < NTYPE; ++o) { pr[o] = expf(acc[o] - mx); sum += pr[o]; }
    float inv = 1.f / sum;
#pragma unroll
    for (int o = 0; o < NTYPE; ++o) pr[o] *= inv;

    float s[12];
    {
        const float4* s4 = (const float4*)(tr + Hn + lane * 12);
        float4 a = s4[0], b = s4[1], c = s4[2];
        s[0] = a.x; s[1] = a.y; s[2]  = a.z; s[3]  = a.w;
        s[4] = b.x; s[5] = b.y; s[6]  = b.z; s[7]  = b.w;
        s[8] = c.x; s[9] = c.y; s[10] = c.z; s[11] = c.w;
    }
    float acc2[NSENS] = {};
    const unsigned short* wt = Wtailbf + (size_t)lane * 12 * WPAD;
    const unsigned short* w2p = Ws2bf + (size_t)lane * 12 * NSENS;
#pragma unroll
    for (int j = 0; j < 12; ++j) {
        short8 a0 = *(const short8*)(wt + j * WPAD);
        short8 a1 = *(const short8*)(wt + j * WPAD + 8);
        ushort4 a2 = *(const ushort4*)(wt + j * WPAD + 16);
        float tl = 0.f;
#pragma unroll
        for (int o = 0; o < 8; ++o) tl += pr[o] * bfu((unsigned short)a0[o]);
#pragma unroll
        for (int o = 0; o < 8; ++o) tl += pr[8 + o] * bfu((unsigned short)a1[o]);
        tl += pr[16] * bfu(a2.x) + pr[17] * bfu(a2.y);
        float v = gelu_exact(s[j] + tl);
        ushort4 wv = *(const ushort4*)(w2p + j * NSENS);
        acc2[0] += v * bfu(wv.x);
        acc2[1] += v * bfu(wv.y);
        acc2[2] += v * bfu(wv.z);
        acc2[3] += v * bfu(wv.w);
    }
#pragma unroll
    for (int o = 0; o < NSENS; ++o)
#pragma unroll
        for (int off = 32; off; off >>= 1) acc2[o] += __shfl_xor(acc2[o], off);
    {
        float lv = 0.f;
#pragma unroll
        for (int o = 0; o < NSENS; ++o) lv = (lane == o) ? (acc2[o] + bs2[o]) : lv;
        if (lane < NSENS) out_sens[row * NSENS + lane] = lv;
    }
}

extern "C" void kernel_launch(void* const* d_in, const int* in_sizes, int n_in,
                              void* d_out, int out_size, void* d_ws, size_t ws_size,
                              hipStream_t stream)
{
    const float* hidden = (const float*)d_in[0];
    const int*   spans  = (const int*)d_in[1];
    const float* wemb   = (const float*)d_in[2];
    const float* Wp     = (const float*)d_in[3];
    const float* bp     = (const float*)d_in[4];
    const float* Wt1    = (const float*)d_in[5];
    const float* bt1    = (const float*)d_in[6];
    const float* Wt2    = (const float*)d_in[7];
    const float* bt2    = (const float*)d_in[8];
    const float* Ws1    = (const float*)d_in[9];
    const float* bs1    = (const float*)d_in[10];
    const float* Ws2    = (const float*)d_in[11];
    const float* bs2    = (const float*)d_in[12];

    float* out      = (float*)d_out;
    float* out_prop = out;
    float* out_type = out + Bn * Sn * 3;
    float* out_sens = out_type + NROW * NTYPE;

    // workspace layout (all 16B-aligned)
    unsigned short* rep = (unsigned short*)d_ws;                 // [4096][2688] bf16
    float* obuf = (float*)(rep + (size_t)NROW * SPAN_DIM);       // [4096][1536] fp32
    unsigned short* WbigT = (unsigned short*)(obuf + (size_t)NROW * NBIG); // [1536][2688] bf16
    unsigned short* Wt2bf   = WbigT + (size_t)NBIG * SPAN_DIM;   // [768][24] bf16
    unsigned short* Wtailbf = Wt2bf + Hn * WPAD;                 // [768][24] bf16
    unsigned short* Ws2bf   = Wtailbf + Hn * WPAD;               // [768][4]  bf16

    pre_kernel<<<NB_TOTAL, 256, 0, stream>>>(
        hidden, spans, wemb, Wp, bp, Wt1, Ws1, Wt2, Ws2,
        out_prop, rep, WbigT, Wt2bf, Wtailbf, Ws2bf);

    gemm_fused<<<768, 256, 0, stream>>>(rep, WbigT, bt1, bs1, obuf);

    heads_kernel<<<NROW / 4, 256, 0, stream>>>(
        obuf, Wt2bf, bt2, Wtailbf, Ws2bf, bs2, out_type, out_sens);
}

// Round 7
// 222.453 us; speedup vs baseline: 1.0340x; 1.0340x over previous
//
#include <hip/hip_runtime.h>
#include <hip/hip_bf16.h>
#include <math.h>

#define Bn 8
#define Sn 2048
#define Hn 768
#define NROW 4096          // B * N_SPANS
#define SPAN_DIM 2688
#define NBIG 1536          // fused GEMM N (768 type-t | 768 sens-pre)
#define NTYPE 18
#define NSENS 4
#define WPAD 24            // padded per-k weight row (shorts), 48 B

// merged pre-kernel block partition
#define NB_PROP 4096
#define NB_SPAN 4096
#define NB_T    2016       // per big transpose (84 x 24 tiles of 32x32)
#define NB_SM   156        // small-weight prep (156*256 = 39936 elems)
#define NB_TOTAL (NB_PROP + NB_SPAN + 2 * NB_T + NB_SM)

typedef __attribute__((ext_vector_type(8))) short short8;
typedef __attribute__((ext_vector_type(4))) float floatx4;

__device__ __forceinline__ unsigned short f2bf(float x) {
    __hip_bfloat16 h = __float2bfloat16(x);
    return *reinterpret_cast<unsigned short*>(&h);
}

__device__ __forceinline__ float bfu(unsigned short u) {
    union { float f; unsigned int i; } v;
    v.i = ((unsigned int)u) << 16;
    return v.f;
}

__device__ __forceinline__ void glds16(const void* g, void* l) {
    __builtin_amdgcn_global_load_lds(
        (const __attribute__((address_space(1))) unsigned int*)g,
        (__attribute__((address_space(3))) unsigned int*)l, 16, 0, 0);
}

__device__ __forceinline__ float gelu_exact(float v) {
    return 0.5f * v * (1.f + erff(v * 0.70710678118654752f));
}

// ============ merged pre-kernel: proposal | span_rep | weight prep ============
__global__ __launch_bounds__(256) void pre_kernel(
    const float* __restrict__ hidden, const int* __restrict__ spans,
    const float* __restrict__ wemb,
    const float* __restrict__ Wp, const float* __restrict__ bp,
    const float* __restrict__ Wt1, const float* __restrict__ Ws1,
    const float* __restrict__ Wt2, const float* __restrict__ Ws2,
    float* __restrict__ out_prop, unsigned short* __restrict__ rep,
    unsigned short* __restrict__ WbigT,
    unsigned short* __restrict__ Wt2bf, unsigned short* __restrict__ Wtailbf,
    unsigned short* __restrict__ Ws2bf)
{
    __shared__ float tile[32][33];
    int id = blockIdx.x;
    int tid = threadIdx.x;

    if (id < NB_PROP) {
        int wave = tid >> 6, lane = tid & 63;
        int row = id * 4 + wave;
        const float4* h4 = (const float4*)(hidden + (size_t)row * Hn);
        float a0 = 0.f, a1 = 0.f, a2 = 0.f;
#pragma unroll
        for (int i = 0; i < 3; ++i) {
            int kc = i * 64 + lane;
            float4 h = h4[kc];
            const float* w = Wp + kc * 12;
            a0 += h.x * w[0] + h.y * w[3] + h.z * w[6] + h.w * w[9];
            a1 += h.x * w[1] + h.y * w[4] + h.z * w[7] + h.w * w[10];
            a2 += h.x * w[2] + h.y * w[5] + h.z * w[8] + h.w * w[11];
        }
#pragma unroll
        for (int off = 32; off; off >>= 1) {
            a0 += __shfl_xor(a0, off);
            a1 += __shfl_xor(a1, off);
            a2 += __shfl_xor(a2, off);
        }
        if (lane < 3) {
            float v = (lane == 0 ? a0 : (lane == 1 ? a1 : a2)) + bp[lane];
            out_prop[row * 3 + lane] = v;
        }
        return;
    }
    id -= NB_PROP;
    if (id < NB_SPAN) {
        if (tid >= 192) return;
        int n = id;
        int b = n >> 9;
        int s = spans[n * 2 + 0];
        int e = spans[n * 2 + 1];
        int w = e - s + 1;
        const float4* hb4 = (const float4*)(hidden + (size_t)b * Sn * Hn);
        unsigned short* r = rep + (size_t)n * SPAN_DIM;
        float inv_w = 1.0f / (float)w;

        float4 sv = hb4[(size_t)s * 192 + tid];
        float4 ev = hb4[(size_t)e * 192 + tid];
        float4 p0 = make_float4(0.f, 0.f, 0.f, 0.f), p1 = p0, p2 = p0, p3 = p0;
        int rr = s;
        for (; rr + 3 <= e; rr += 4) {
            float4 h0 = hb4[(size_t)(rr + 0) * 192 + tid];
            float4 h1 = hb4[(size_t)(rr + 1) * 192 + tid];
            float4 h2 = hb4[(size_t)(rr + 2) * 192 + tid];
            float4 h3 = hb4[(size_t)(rr + 3) * 192 + tid];
            p0.x += h0.x; p0.y += h0.y; p0.z += h0.z; p0.w += h0.w;
            p1.x += h1.x; p1.y += h1.y; p1.z += h1.z; p1.w += h1.w;
            p2.x += h2.x; p2.y += h2.y; p2.z += h2.z; p2.w += h2.w;
            p3.x += h3.x; p3.y += h3.y; p3.z += h3.z; p3.w += h3.w;
        }
        for (; rr <= e; ++rr) {
            float4 h = hb4[(size_t)rr * 192 + tid];
            p0.x += h.x; p0.y += h.y; p0.z += h.z; p0.w += h.w;
        }
        float4 pv;
        pv.x = ((p0.x + p1.x) + (p2.x + p3.x)) * inv_w;
        pv.y = ((p0.y + p1.y) + (p2.y + p3.y)) * inv_w;
        pv.z = ((p0.z + p1.z) + (p2.z + p3.z)) * inv_w;
        pv.w = ((p0.w + p1.w) + (p2.w + p3.w)) * inv_w;

        *(ushort4*)&r[tid * 4] =
            make_ushort4(f2bf(sv.x), f2bf(sv.y), f2bf(sv.z), f2bf(sv.w));
        *(ushort4*)&r[Hn + tid * 4] =
            make_ushort4(f2bf(ev.x), f2bf(ev.y), f2bf(ev.z), f2bf(ev.w));
        *(ushort4*)&r[2 * Hn + tid * 4] =
            make_ushort4(f2bf(pv.x), f2bf(pv.y), f2bf(pv.z), f2bf(pv.w));
        if (tid < 96) {
            int wi = w > 63 ? 63 : w;
            float4 wv = ((const float4*)wemb)[wi * 96 + tid];
            *(ushort4*)&r[3 * Hn + tid * 4] =
                make_ushort4(f2bf(wv.x), f2bf(wv.y), f2bf(wv.z), f2bf(wv.w));
        }
        return;
    }
    id -= NB_SPAN;
    if (id < 2 * NB_T) {
        int z = id / NB_T, l = id - z * NB_T;
        const float* W = (z == 0) ? Wt1 : Ws1;
        unsigned short* Wt = WbigT + (size_t)z * Hn * SPAN_DIM;
        int k0 = (l % 84) * 32, n0 = (l / 84) * 32;
        int tx = tid & 31, ty = tid >> 5;
#pragma unroll
        for (int i = 0; i < 32; i += 8)
            tile[ty + i][tx] = W[(size_t)(k0 + ty + i) * Hn + n0 + tx];
        __syncthreads();
#pragma unroll
        for (int i = 0; i < 32; i += 8)
            Wt[(size_t)(n0 + ty + i) * SPAN_DIM + k0 + tx] = f2bf(tile[tx][ty + i]);
        return;
    }
    id -= 2 * NB_T;
    {
        int idx = id * 256 + tid;
        const int N1 = Hn * WPAD;
        const int N2 = 2 * N1;
        const int N3 = N2 + Hn * NSENS;
        if (idx < N1) {
            int k = idx / WPAD, o = idx - k * WPAD;
            Wt2bf[idx] = (o < NTYPE) ? f2bf(Wt2[k * NTYPE + o]) : 0;
        } else if (idx < N2) {
            int j = idx - N1;
            int k = j / WPAD, o = j - k * WPAD;
            Wtailbf[j] = (o < NTYPE) ? f2bf(Ws1[(size_t)(SPAN_DIM + o) * Hn + k]) : 0;
        } else if (idx < N3) {
            int j = idx - N2;
            Ws2bf[j] = f2bf(Ws2[j]);
        }
    }
}

// ===== fused bf16 MFMA GEMM: 128x128 tile, BK=64, 4 waves each 64x64 =====
// obuf (bf16) = epilogue(rep @ WbigT^T). Single-buffer swizzled glds16 staging.
__global__ __launch_bounds__(256, 2) void gemm_fused(
    const unsigned short* __restrict__ A,
    const unsigned short* __restrict__ Bt,
    const float* __restrict__ bt1, const float* __restrict__ bs1,
    unsigned short* __restrict__ obuf)
{
    const int BK = 64;
    __shared__ unsigned short As[128 * BK];   // 16 KB
    __shared__ unsigned short Bs[128 * BK];   // 16 KB

    int tid = threadIdx.x, wave = tid >> 6, lane = tid & 63;
    int m0 = blockIdx.x * 128, n0 = blockIdx.y * 128;

    int wr = (wave >> 1) * 64;      // 2x2 waves of 64x64
    int wc = (wave & 1) * 64;
    int fr = lane & 15;
    int fc = lane >> 4;             // 0..3 (16B chunk within 32-k window)

    // staging: chunk d = tid + j*256 (j=0..3), r=d>>3, swizzled col c=(d&7)^(r&7)
    const unsigned short* gA[4];
    const unsigned short* gB[4];
#pragma unroll
    for (int j = 0; j < 4; ++j) {
        int d = tid + j * 256;
        int r = d >> 3, c = (d & 7) ^ (r & 7);
        gA[j] = A + (size_t)(m0 + r) * SPAN_DIM + c * 8;
        gB[j] = Bt + (size_t)(n0 + r) * SPAN_DIM + c * 8;
    }
    int off[4];
#pragma unroll
    for (int j = 0; j < 4; ++j) off[j] = j * 2048 + wave * 512;

    floatx4 acc[4][4] = {};

    for (int k0 = 0; k0 < SPAN_DIM; k0 += BK) {
        glds16(gA[0] + k0, &As[off[0]]);
        glds16(gA[1] + k0, &As[off[1]]);
        glds16(gA[2] + k0, &As[off[2]]);
        glds16(gA[3] + k0, &As[off[3]]);
        glds16(gB[0] + k0, &Bs[off[0]]);
        glds16(gB[1] + k0, &Bs[off[1]]);
        glds16(gB[2] + k0, &Bs[off[2]]);
        glds16(gB[3] + k0, &Bs[off[3]]);
        __syncthreads();

#pragma unroll
        for (int half = 0; half < 2; ++half) {
            int cb = half * 4 + fc;
            short8 af[4], bf[4];
#pragma unroll
            for (int i = 0; i < 4; ++i) {
                int r = wr + i * 16 + fr;
                af[i] = *(const short8*)&As[((r << 3) | (cb ^ (r & 7))) * 8];
            }
#pragma unroll
            for (int i = 0; i < 4; ++i) {
                int r = wc + i * 16 + fr;
                bf[i] = *(const short8*)&Bs[((r << 3) | (cb ^ (r & 7))) * 8];
            }
#pragma unroll
            for (int mi = 0; mi < 4; ++mi)
#pragma unroll
                for (int ni = 0; ni < 4; ++ni)
                    acc[mi][ni] = __builtin_amdgcn_mfma_f32_16x16x32_bf16(
                        af[mi], bf[ni], acc[mi][ni], 0, 0, 0);
        }
        __syncthreads();
    }

    bool isT = (n0 < Hn);
    const float* bias = isT ? bt1 : (bs1 - Hn);
    int cr = (lane >> 4) * 4;
#pragma unroll
    for (int mi = 0; mi < 4; ++mi) {
#pragma unroll
        for (int ni = 0; ni < 4; ++ni) {
            int col = n0 + wc + ni * 16 + fr;
            float bv = bias[col];
#pragma unroll
            for (int r = 0; r < 4; ++r) {
                int row = m0 + wr + mi * 16 + cr + r;
                float v = acc[mi][ni][r] + bv;
                if (isT) v = gelu_exact(v);
                obuf[(size_t)row * NBIG + col] = f2bf(v);
            }
        }
    }
}

// --- fused heads on bf16 obuf: lane owns ushort4 chunks (k = 4*(lane+i*64)+j) ---
__global__ __launch_bounds__(256) void heads_kernel(
    const unsigned short* __restrict__ obuf, const unsigned short* __restrict__ Wt2bf,
    const float* __restrict__ bt2, const unsigned short* __restrict__ Wtailbf,
    const unsigned short* __restrict__ Ws2bf, const float* __restrict__ bs2,
    float* __restrict__ out_type, float* __restrict__ out_sens)
{
    int wave = threadIdx.x >> 6, lane = threadIdx.x & 63;
    int row = blockIdx.x * 4 + wave;
    const ushort4* tr4 = (const ushort4*)(obuf + (size_t)row * NBIG);

    // ---- type logits: t chunk c = lane + i*64 covers k = 4c..4c+3 ----
    float acc[NTYPE] = {};
#pragma unroll
    for (int i = 0; i < 3; ++i) {
        ushort4 tc = tr4[lane + i * 64];
        float tv[4] = {bfu(tc.x), bfu(tc.y), bfu(tc.z), bfu(tc.w)};
#pragma unroll
        for (int j = 0; j < 4; ++j) {
            int k = (lane + i * 64) * 4 + j;
            const unsigned short* wp = Wt2bf + (size_t)k * WPAD;
            short8 w0 = *(const short8*)wp;
            short8 w1 = *(const short8*)(wp + 8);
            ushort4 w2 = *(const ushort4*)(wp + 16);
#pragma unroll
            for (int o = 0; o < 8; ++o) acc[o] += tv[j] * bfu((unsigned short)w0[o]);
#pragma unroll
            for (int o = 0; o < 8; ++o) acc[8 + o] += tv[j] * bfu((unsigned short)w1[o]);
            acc[16] += tv[j] * bfu(w2.x);
            acc[17] += tv[j] * bfu(w2.y);
        }
    }
#pragma unroll
    for (int o = 0; o < NTYPE; ++o)
#pragma unroll
        for (int off = 32; off; off >>= 1) acc[o] += __shfl_xor(acc[o], off);

    float mx = -1e30f;
#pragma unroll
    for (int o = 0; o < NTYPE; ++o) { acc[o] += bt2[o]; mx = fmaxf(mx, acc[o]); }
    {
        float lv = 0.f;
#pragma unroll
        for (int o = 0; o < NTYPE; ++o) lv = (lane == o) ? acc[o] : lv;
        if (lane < NTYPE) out_type[row * NTYPE + lane] = lv;
    }
    float pr[NTYPE], sum = 0.f;
#pragma unroll
    for (int o = 0; o < NTYPE; ++o) { pr[o] = expf(acc[o] - mx); sum += pr[o]; }
    float inv = 1.f / sum;
#pragma unroll
    for (int o = 0; o < NTYPE; ++o) pr[o] *= inv;

    // ---- tail correction + GELU + sens head ----
    const ushort4* sp4 = (const ushort4*)(obuf + (size_t)row * NBIG + Hn);
    float acc2[NSENS] = {};
#pragma unroll
    for (int i = 0; i < 3; ++i) {
        ushort4 sc = sp4[lane + i * 64];
        float sv[4] = {bfu(sc.x), bfu(sc.y), bfu(sc.z), bfu(sc.w)};
#pragma unroll
        for (int j = 0; j < 4; ++j) {
            int k = (lane + i * 64) * 4 + j;
            const unsigned short* wt = Wtailbf + (size_t)k * WPAD;
            short8 a0 = *(const short8*)wt;
            short8 a1 = *(const short8*)(wt + 8);
            ushort4 a2 = *(const ushort4*)(wt + 16);
            float tl = 0.f;
#pragma unroll
            for (int o = 0; o < 8; ++o) tl += pr[o] * bfu((unsigned short)a0[o]);
#pragma unroll
            for (int o = 0; o < 8; ++o) tl += pr[8 + o] * bfu((unsigned short)a1[o]);
            tl += pr[16] * bfu(a2.x) + pr[17] * bfu(a2.y);
            float v = gelu_exact(sv[j] + tl);
            ushort4 wv = *(const ushort4*)(Ws2bf + (size_t)k * NSENS);
            acc2[0] += v * bfu(wv.x);
            acc2[1] += v * bfu(wv.y);
            acc2[2] += v * bfu(wv.z);
            acc2[3] += v * bfu(wv.w);
        }
    }
#pragma unroll
    for (int o = 0; o < NSENS; ++o)
#pragma unroll
        for (int off = 32; off; off >>= 1) acc2[o] += __shfl_xor(acc2[o], off);
    {
        float lv = 0.f;
#pragma unroll
        for (int o = 0; o < NSENS; ++o) lv = (lane == o) ? (acc2[o] + bs2[o]) : lv;
        if (lane < NSENS) out_sens[row * NSENS + lane] = lv;
    }
}

extern "C" void kernel_launch(void* const* d_in, const int* in_sizes, int n_in,
                              void* d_out, int out_size, void* d_ws, size_t ws_size,
                              hipStream_t stream)
{
    const float* hidden = (const float*)d_in[0];
    const int*   spans  = (const int*)d_in[1];
    const float* wemb   = (const float*)d_in[2];
    const float* Wp     = (const float*)d_in[3];
    const float* bp     = (const float*)d_in[4];
    const float* Wt1    = (const float*)d_in[5];
    const float* bt1    = (const float*)d_in[6];
    const float* Wt2    = (const float*)d_in[7];
    const float* bt2    = (const float*)d_in[8];
    const float* Ws1    = (const float*)d_in[9];
    const float* bs1    = (const float*)d_in[10];
    const float* Ws2    = (const float*)d_in[11];
    const float* bs2    = (const float*)d_in[12];

    float* out      = (float*)d_out;
    float* out_prop = out;
    float* out_type = out + Bn * Sn * 3;
    float* out_sens = out_type + NROW * NTYPE;

    // workspace layout (all 16B-aligned)
    unsigned short* rep  = (unsigned short*)d_ws;                // [4096][2688] bf16
    unsigned short* obuf = rep + (size_t)NROW * SPAN_DIM;        // [4096][1536] bf16
    unsigned short* WbigT = obuf + (size_t)NROW * NBIG;          // [1536][2688] bf16
    unsigned short* Wt2bf   = WbigT + (size_t)NBIG * SPAN_DIM;   // [768][24] bf16
    unsigned short* Wtailbf = Wt2bf + Hn * WPAD;                 // [768][24] bf16
    unsigned short* Ws2bf   = Wtailbf + Hn * WPAD;               // [768][4]  bf16

    pre_kernel<<<NB_TOTAL, 256, 0, stream>>>(
        hidden, spans, wemb, Wp, bp, Wt1, Ws1, Wt2, Ws2,
        out_prop, rep, WbigT, Wt2bf, Wtailbf, Ws2bf);

    dim3 gg(NROW / 128, NBIG / 128);   // 32 x 12 = 384 blocks
    gemm_fused<<<gg, 256, 0, stream>>>(rep, WbigT, bt1, bs1, obuf);

    heads_kernel<<<NROW / 4, 256, 0, stream>>>(
        obuf, Wt2bf, bt2, Wtailbf, Ws2bf, bs2, out_type, out_sens);
}

// Round 8
// 217.847 us; speedup vs baseline: 1.0559x; 1.0211x over previous
//
#include <hip/hip_runtime.h>
#include <hip/hip_bf16.h>
#include <math.h>

#define Bn 8
#define Sn 2048
#define Hn 768
#define NROW 4096          // B * N_SPANS
#define SPAN_DIM 2688
#define NBIG 1536          // fused GEMM N (768 type-t | 768 sens-pre)
#define NTYPE 18
#define NSENS 4
#define WPAD 24            // padded per-k weight row (shorts), 48 B

// merged pre-kernel block partition
#define NB_PROP 4096
#define NB_SPAN 4096
#define NB_T    2016       // per big transpose (84 x 24 tiles of 32x32)
#define NB_SM   156        // small-weight prep
#define NB_TOTAL (NB_PROP + NB_SPAN + 2 * NB_T + NB_SM)

typedef __attribute__((ext_vector_type(8))) short short8;
typedef __attribute__((ext_vector_type(4))) float floatx4;

__device__ __forceinline__ unsigned short f2bf(float x) {
    __hip_bfloat16 h = __float2bfloat16(x);
    return *reinterpret_cast<unsigned short*>(&h);
}

__device__ __forceinline__ float bfu(unsigned short u) {
    union { float f; unsigned int i; } v;
    v.i = ((unsigned int)u) << 16;
    return v.f;
}

__device__ __forceinline__ void glds16(const void* g, void* l) {
    __builtin_amdgcn_global_load_lds(
        (const __attribute__((address_space(1))) unsigned int*)g,
        (__attribute__((address_space(3))) unsigned int*)l, 16, 0, 0);
}

__device__ __forceinline__ float gelu_exact(float v) {
    return 0.5f * v * (1.f + erff(v * 0.70710678118654752f));
}

// ============ merged pre-kernel: proposal | span_rep | weight prep ============
__global__ __launch_bounds__(256) void pre_kernel(
    const float* __restrict__ hidden, const int* __restrict__ spans,
    const float* __restrict__ wemb,
    const float* __restrict__ Wp, const float* __restrict__ bp,
    const float* __restrict__ Wt1, const float* __restrict__ Ws1,
    const float* __restrict__ Wt2, const float* __restrict__ Ws2,
    float* __restrict__ out_prop, unsigned short* __restrict__ rep,
    unsigned short* __restrict__ WbigT,
    unsigned short* __restrict__ Wt2bf, unsigned short* __restrict__ Wtailbf,
    unsigned short* __restrict__ Ws2bf)
{
    __shared__ float tile[32][33];
    int id = blockIdx.x;
    int tid = threadIdx.x;

    if (id < NB_PROP) {
        int wave = tid >> 6, lane = tid & 63;
        int row = id * 4 + wave;
        const float4* h4 = (const float4*)(hidden + (size_t)row * Hn);
        float a0 = 0.f, a1 = 0.f, a2 = 0.f;
#pragma unroll
        for (int i = 0; i < 3; ++i) {
            int kc = i * 64 + lane;
            float4 h = h4[kc];
            const float* w = Wp + kc * 12;
            a0 += h.x * w[0] + h.y * w[3] + h.z * w[6] + h.w * w[9];
            a1 += h.x * w[1] + h.y * w[4] + h.z * w[7] + h.w * w[10];
            a2 += h.x * w[2] + h.y * w[5] + h.z * w[8] + h.w * w[11];
        }
#pragma unroll
        for (int off = 32; off; off >>= 1) {
            a0 += __shfl_xor(a0, off);
            a1 += __shfl_xor(a1, off);
            a2 += __shfl_xor(a2, off);
        }
        if (lane < 3) {
            float v = (lane == 0 ? a0 : (lane == 1 ? a1 : a2)) + bp[lane];
            out_prop[row * 3 + lane] = v;
        }
        return;
    }
    id -= NB_PROP;
    if (id < NB_SPAN) {
        if (tid >= 192) return;
        int n = id;
        int b = n >> 9;
        int s = spans[n * 2 + 0];
        int e = spans[n * 2 + 1];
        int w = e - s + 1;
        const float4* hb4 = (const float4*)(hidden + (size_t)b * Sn * Hn);
        unsigned short* r = rep + (size_t)n * SPAN_DIM;
        float inv_w = 1.0f / (float)w;

        float4 sv = hb4[(size_t)s * 192 + tid];
        float4 ev = hb4[(size_t)e * 192 + tid];
        float4 p0 = make_float4(0.f, 0.f, 0.f, 0.f), p1 = p0, p2 = p0, p3 = p0;
        int rr = s;
        for (; rr + 3 <= e; rr += 4) {
            float4 h0 = hb4[(size_t)(rr + 0) * 192 + tid];
            float4 h1 = hb4[(size_t)(rr + 1) * 192 + tid];
            float4 h2 = hb4[(size_t)(rr + 2) * 192 + tid];
            float4 h3 = hb4[(size_t)(rr + 3) * 192 + tid];
            p0.x += h0.x; p0.y += h0.y; p0.z += h0.z; p0.w += h0.w;
            p1.x += h1.x; p1.y += h1.y; p1.z += h1.z; p1.w += h1.w;
            p2.x += h2.x; p2.y += h2.y; p2.z += h2.z; p2.w += h2.w;
            p3.x += h3.x; p3.y += h3.y; p3.z += h3.z; p3.w += h3.w;
        }
        for (; rr <= e; ++rr) {
            float4 h = hb4[(size_t)rr * 192 + tid];
            p0.x += h.x; p0.y += h.y; p0.z += h.z; p0.w += h.w;
        }
        float4 pv;
        pv.x = ((p0.x + p1.x) + (p2.x + p3.x)) * inv_w;
        pv.y = ((p0.y + p1.y) + (p2.y + p3.y)) * inv_w;
        pv.z = ((p0.z + p1.z) + (p2.z + p3.z)) * inv_w;
        pv.w = ((p0.w + p1.w) + (p2.w + p3.w)) * inv_w;

        *(ushort4*)&r[tid * 4] =
            make_ushort4(f2bf(sv.x), f2bf(sv.y), f2bf(sv.z), f2bf(sv.w));
        *(ushort4*)&r[Hn + tid * 4] =
            make_ushort4(f2bf(ev.x), f2bf(ev.y), f2bf(ev.z), f2bf(ev.w));
        *(ushort4*)&r[2 * Hn + tid * 4] =
            make_ushort4(f2bf(pv.x), f2bf(pv.y), f2bf(pv.z), f2bf(pv.w));
        if (tid < 96) {
            int wi = w > 63 ? 63 : w;
            float4 wv = ((const float4*)wemb)[wi * 96 + tid];
            *(ushort4*)&r[3 * Hn + tid * 4] =
                make_ushort4(f2bf(wv.x), f2bf(wv.y), f2bf(wv.z), f2bf(wv.w));
        }
        return;
    }
    id -= NB_SPAN;
    if (id < 2 * NB_T) {
        int z = id / NB_T, l = id - z * NB_T;
        const float* W = (z == 0) ? Wt1 : Ws1;
        unsigned short* Wt = WbigT + (size_t)z * Hn * SPAN_DIM;
        int k0 = (l % 84) * 32, n0 = (l / 84) * 32;
        int tx = tid & 31, ty = tid >> 5;
#pragma unroll
        for (int i = 0; i < 32; i += 8)
            tile[ty + i][tx] = W[(size_t)(k0 + ty + i) * Hn + n0 + tx];
        __syncthreads();
#pragma unroll
        for (int i = 0; i < 32; i += 8)
            Wt[(size_t)(n0 + ty + i) * SPAN_DIM + k0 + tx] = f2bf(tile[tx][ty + i]);
        return;
    }
    id -= 2 * NB_T;
    {
        int idx = id * 256 + tid;
        const int N1 = Hn * WPAD;
        const int N2 = 2 * N1;
        const int N3 = N2 + Hn * NSENS;
        if (idx < N1) {
            int k = idx / WPAD, o = idx - k * WPAD;
            Wt2bf[idx] = (o < NTYPE) ? f2bf(Wt2[k * NTYPE + o]) : 0;
        } else if (idx < N2) {
            int j = idx - N1;
            int k = j / WPAD, o = j - k * WPAD;
            Wtailbf[j] = (o < NTYPE) ? f2bf(Ws1[(size_t)(SPAN_DIM + o) * Hn + k]) : 0;
        } else if (idx < N3) {
            int j = idx - N2;
            Ws2bf[j] = f2bf(Ws2[j]);
        }
    }
}

// ===== fused bf16 MFMA GEMM, K-split waves: BM=128, BN=64, BK=64 =====
// 4 waves = (m-half, k-half); each wave computes a 64x64 output tile over
// half the K-window per iter (8 ds_read_b128 : 16 MFMA). Partial sums
// reduced across k-halves through LDS at the end.
__global__ __launch_bounds__(256, 3) void gemm_fused(
    const unsigned short* __restrict__ A,
    const unsigned short* __restrict__ Bt,
    const float* __restrict__ bt1, const float* __restrict__ bs1,
    unsigned short* __restrict__ obuf)
{
    const int BK = 64;
    __shared__ __align__(16) unsigned char smem[32768];
    unsigned short* As = (unsigned short*)smem;          // [128][64] 16 KB
    unsigned short* Bs = As + 128 * BK;                  // [64][64]   8 KB

    int tid = threadIdx.x, wave = tid >> 6, lane = tid & 63;
    int m0 = blockIdx.x * 128, n0 = blockIdx.y * 64;

    int mh = wave >> 1;             // m-half: rows mh*64..+63
    int kh = wave & 1;              // k-half: K-window kh*32..+31 within BK
    int fr = lane & 15;
    int fq = lane >> 4;             // 0..3: 16B chunk within the 32-k window

    // staging: chunk d, r=d>>3, swizzled col c=(d&7)^(r&7)
    const unsigned short* gA[4];
#pragma unroll
    for (int j = 0; j < 4; ++j) {
        int d = tid + j * 256;
        int r = d >> 3, c = (d & 7) ^ (r & 7);
        gA[j] = A + (size_t)(m0 + r) * SPAN_DIM + c * 8;
    }
    const unsigned short* gB[2];
#pragma unroll
    for (int j = 0; j < 2; ++j) {
        int d = tid + j * 256;
        int r = d >> 3, c = (d & 7) ^ (r & 7);
        gB[j] = Bt + (size_t)(n0 + r) * SPAN_DIM + c * 8;
    }
    int offA[4], offB[2];
#pragma unroll
    for (int j = 0; j < 4; ++j) offA[j] = j * 2048 + wave * 512;
#pragma unroll
    for (int j = 0; j < 2; ++j) offB[j] = j * 2048 + wave * 512;

    floatx4 acc[4][4] = {};
    int cb = kh * 4 + fq;           // this wave's K-chunk column in LDS

    for (int k0 = 0; k0 < SPAN_DIM; k0 += BK) {
        glds16(gA[0] + k0, &As[offA[0]]);
        glds16(gA[1] + k0, &As[offA[1]]);
        glds16(gA[2] + k0, &As[offA[2]]);
        glds16(gA[3] + k0, &As[offA[3]]);
        glds16(gB[0] + k0, &Bs[offB[0]]);
        glds16(gB[1] + k0, &Bs[offB[1]]);
        __syncthreads();

        short8 af[4], bf[4];
#pragma unroll
        for (int i = 0; i < 4; ++i) {
            int r = mh * 64 + i * 16 + fr;
            af[i] = *(const short8*)&As[((r << 3) | (cb ^ (r & 7))) * 8];
        }
#pragma unroll
        for (int i = 0; i < 4; ++i) {
            int r = i * 16 + fr;
            bf[i] = *(const short8*)&Bs[((r << 3) | (cb ^ (r & 7))) * 8];
        }
#pragma unroll
        for (int mi = 0; mi < 4; ++mi)
#pragma unroll
            for (int ni = 0; ni < 4; ++ni)
                acc[mi][ni] = __builtin_amdgcn_mfma_f32_16x16x32_bf16(
                    af[mi], bf[ni], acc[mi][ni], 0, 0, 0);
        __syncthreads();
    }

    // ---- cross-k-half reduce through LDS, then epilogue by kh==0 waves ----
    float* red = (float*)smem;                 // [2][64*64] fp32 (32 KB)
    float* myred = red + mh * 4096;
    int cr = (lane >> 4) * 4;
    if (kh == 1) {
#pragma unroll
        for (int mi = 0; mi < 4; ++mi)
#pragma unroll
            for (int ni = 0; ni < 4; ++ni)
#pragma unroll
                for (int r = 0; r < 4; ++r)
                    myred[(mi * 16 + cr + r) * 64 + ni * 16 + fr] = acc[mi][ni][r];
    }
    __syncthreads();
    if (kh == 0) {
        bool isT = (n0 < Hn);
        const float* bias = isT ? bt1 : (bs1 - Hn);
#pragma unroll
        for (int mi = 0; mi < 4; ++mi) {
#pragma unroll
            for (int ni = 0; ni < 4; ++ni) {
                int col = n0 + ni * 16 + fr;
                float bv = bias[col];
#pragma unroll
                for (int r = 0; r < 4; ++r) {
                    int row = m0 + mh * 64 + mi * 16 + cr + r;
                    float v = acc[mi][ni][r] +
                              myred[(mi * 16 + cr + r) * 64 + ni * 16 + fr] + bv;
                    if (isT) v = gelu_exact(v);
                    obuf[(size_t)row * NBIG + col] = f2bf(v);
                }
            }
        }
    }
}

// --- fused heads on bf16 obuf: lane owns ushort4 chunks (k = 4*(lane+i*64)+j) ---
__global__ __launch_bounds__(256) void heads_kernel(
    const unsigned short* __restrict__ obuf, const unsigned short* __restrict__ Wt2bf,
    const float* __restrict__ bt2, const unsigned short* __restrict__ Wtailbf,
    const unsigned short* __restrict__ Ws2bf, const float* __restrict__ bs2,
    float* __restrict__ out_type, float* __restrict__ out_sens)
{
    int wave = threadIdx.x >> 6, lane = threadIdx.x & 63;
    int row = blockIdx.x * 4 + wave;
    const ushort4* tr4 = (const ushort4*)(obuf + (size_t)row * NBIG);

    float acc[NTYPE] = {};
#pragma unroll
    for (int i = 0; i < 3; ++i) {
        ushort4 tc = tr4[lane + i * 64];
        float tv[4] = {bfu(tc.x), bfu(tc.y), bfu(tc.z), bfu(tc.w)};
#pragma unroll
        for (int j = 0; j < 4; ++j) {
            int k = (lane + i * 64) * 4 + j;
            const unsigned short* wp = Wt2bf + (size_t)k * WPAD;
            short8 w0 = *(const short8*)wp;
            short8 w1 = *(const short8*)(wp + 8);
            ushort4 w2 = *(const ushort4*)(wp + 16);
#pragma unroll
            for (int o = 0; o < 8; ++o) acc[o] += tv[j] * bfu((unsigned short)w0[o]);
#pragma unroll
            for (int o = 0; o < 8; ++o) acc[8 + o] += tv[j] * bfu((unsigned short)w1[o]);
            acc[16] += tv[j] * bfu(w2.x);
            acc[17] += tv[j] * bfu(w2.y);
        }
    }
#pragma unroll
    for (int o = 0; o < NTYPE; ++o)
#pragma unroll
        for (int off = 32; off; off >>= 1) acc[o] += __shfl_xor(acc[o], off);

    float mx = -1e30f;
#pragma unroll
    for (int o = 0; o < NTYPE; ++o) { acc[o] += bt2[o]; mx = fmaxf(mx, acc[o]); }
    {
        float lv = 0.f;
#pragma unroll
        for (int o = 0; o < NTYPE; ++o) lv = (lane == o) ? acc[o] : lv;
        if (lane < NTYPE) out_type[row * NTYPE + lane] = lv;
    }
    float pr[NTYPE], sum = 0.f;
#pragma unroll
    for (int o = 0; o < NTYPE; ++o) { pr[o] = expf(acc[o] - mx); sum += pr[o]; }
    float inv = 1.f / sum;
#pragma unroll
    for (int o = 0; o < NTYPE; ++o) pr[o] *= inv;

    const ushort4* sp4 = (const ushort4*)(obuf + (size_t)row * NBIG + Hn);
    float acc2[NSENS] = {};
#pragma unroll
    for (int i = 0; i < 3; ++i) {
        ushort4 sc = sp4[lane + i * 64];
        float sv[4] = {bfu(sc.x), bfu(sc.y), bfu(sc.z), bfu(sc.w)};
#pragma unroll
        for (int j = 0; j < 4; ++j) {
            int k = (lane + i * 64) * 4 + j;
            const unsigned short* wt = Wtailbf + (size_t)k * WPAD;
            short8 a0 = *(const short8*)wt;
            short8 a1 = *(const short8*)(wt + 8);
            ushort4 a2 = *(const ushort4*)(wt + 16);
            float tl = 0.f;
#pragma unroll
            for (int o = 0; o < 8; ++o) tl += pr[o] * bfu((unsigned short)a0[o]);
#pragma unroll
            for (int o = 0; o < 8; ++o) tl += pr[8 + o] * bfu((unsigned short)a1[o]);
            tl += pr[16] * bfu(a2.x) + pr[17] * bfu(a2.y);
            float v = gelu_exact(sv[j] + tl);
            ushort4 wv = *(const ushort4*)(Ws2bf + (size_t)k * NSENS);
            acc2[0] += v * bfu(wv.x);
            acc2[1] += v * bfu(wv.y);
            acc2[2] += v * bfu(wv.z);
            acc2[3] += v * bfu(wv.w);
        }
    }
#pragma unroll
    for (int o = 0; o < NSENS; ++o)
#pragma unroll
        for (int off = 32; off; off >>= 1) acc2[o] += __shfl_xor(acc2[o], off);
    {
        float lv = 0.f;
#pragma unroll
        for (int o = 0; o < NSENS; ++o) lv = (lane == o) ? (acc2[o] + bs2[o]) : lv;
        if (lane < NSENS) out_sens[row * NSENS + lane] = lv;
    }
}

extern "C" void kernel_launch(void* const* d_in, const int* in_sizes, int n_in,
                              void* d_out, int out_size, void* d_ws, size_t ws_size,
                              hipStream_t stream)
{
    const float* hidden = (const float*)d_in[0];
    const int*   spans  = (const int*)d_in[1];
    const float* wemb   = (const float*)d_in[2];
    const float* Wp     = (const float*)d_in[3];
    const float* bp     = (const float*)d_in[4];
    const float* Wt1    = (const float*)d_in[5];
    const float* bt1    = (const float*)d_in[6];
    const float* Wt2    = (const float*)d_in[7];
    const float* bt2    = (const float*)d_in[8];
    const float* Ws1    = (const float*)d_in[9];
    const float* bs1    = (const float*)d_in[10];
    const float* Ws2    = (const float*)d_in[11];
    const float* bs2    = (const float*)d_in[12];

    float* out      = (float*)d_out;
    float* out_prop = out;
    float* out_type = out + Bn * Sn * 3;
    float* out_sens = out_type + NROW * NTYPE;

    // workspace layout (all 16B-aligned)
    unsigned short* rep  = (unsigned short*)d_ws;                // [4096][2688] bf16
    unsigned short* obuf = rep + (size_t)NROW * SPAN_DIM;        // [4096][1536] bf16
    unsigned short* WbigT = obuf + (size_t)NROW * NBIG;          // [1536][2688] bf16
    unsigned short* Wt2bf   = WbigT + (size_t)NBIG * SPAN_DIM;   // [768][24] bf16
    unsigned short* Wtailbf = Wt2bf + Hn * WPAD;                 // [768][24] bf16
    unsigned short* Ws2bf   = Wtailbf + Hn * WPAD;               // [768][4]  bf16

    pre_kernel<<<NB_TOTAL, 256, 0, stream>>>(
        hidden, spans, wemb, Wp, bp, Wt1, Ws1, Wt2, Ws2,
        out_prop, rep, WbigT, Wt2bf, Wtailbf, Ws2bf);

    dim3 gg(NROW / 128, NBIG / 64);   // 32 x 24 = 768 blocks = 3/CU
    gemm_fused<<<gg, 256, 0, stream>>>(rep, WbigT, bt1, bs1, obuf);

    heads_kernel<<<NROW / 4, 256, 0, stream>>>(
        obuf, Wt2bf, bt2, Wtailbf, Ws2bf, bs2, out_type, out_sens);
}